// Round 1
// baseline (601.811 us; speedup 1.0000x reference)
//
#include <hip/hip_runtime.h>
#include <hip/hip_bf16.h>

#define S_LEN 2048
#define HID   4096
#define NH    32
#define NKV   8
#define HD    128

typedef __attribute__((ext_vector_type(8))) short short8v;
typedef __attribute__((ext_vector_type(4))) float floatx4;

__device__ __forceinline__ float bf2f(unsigned short u) {
  union { unsigned int u32; float f; } v; v.u32 = ((unsigned int)u) << 16; return v.f;
}
__device__ __forceinline__ unsigned short f2bf(float f) {
  union { float f; unsigned int u; } v; v.f = f;
  unsigned int u = v.u + 0x7fffu + ((v.u >> 16) & 1u);
  return (unsigned short)(u >> 16);
}

__device__ __forceinline__ void gld_lds16(const void* g, void* l) {
  __builtin_amdgcn_global_load_lds((const __attribute__((address_space(1))) void*)g,
                                   (__attribute__((address_space(3))) void*)l, 16, 0, 0);
}

// ---------------- f32 -> bf16 convert (vectorized, grid-stride) ----------------
__global__ __launch_bounds__(256) void cvt_f32_bf16(const float* __restrict__ in,
                                                    unsigned short* __restrict__ out, int n4) {
  int i = blockIdx.x * blockDim.x + threadIdx.x;
  int stride = gridDim.x * blockDim.x;
  for (; i < n4; i += stride) {
    float4 v = ((const float4*)in)[i];
    ushort4 o;
    o.x = f2bf(v.x); o.y = f2bf(v.y); o.z = f2bf(v.z); o.w = f2bf(v.w);
    ((ushort4*)out)[i] = o;
  }
}

// ---------------- bf16 GEMM, C[m,n] = sum_k A[m,k]*B[n,k]  (both row-major, K contiguous)
// m97 structure: 128x128 tile, BK=32, 4 waves (2x2), wave = 64x64 = 4x4 frags 16x16x32.
// MODE 0: bf16 C[row*N+col]   MODE 1: bf16 transposed C[col*M+row] (packed 4)   MODE 2: f32 C
template <int MODE>
__global__ __launch_bounds__(256) void gemm_bt(const unsigned short* __restrict__ A,
                                               const unsigned short* __restrict__ B,
                                               void* __restrict__ C,
                                               int M, int N, int K) {
  __shared__ unsigned short ldsA[128 * 32];
  __shared__ unsigned short ldsB[128 * 32];
  const int tid = threadIdx.x;
  const int w = tid >> 6, lane = tid & 63;
  const int fr = lane & 15, fq = lane >> 4;
  const int brow = blockIdx.y * 128, bcol = blockIdx.x * 128;
  const int wr = w >> 1, wc = w & 1;

  const unsigned short* pA = A + (size_t)(brow + (tid >> 2)) * K + (tid & 3) * 8;
  const unsigned short* pB = B + (size_t)(bcol + (tid >> 2)) * K + (tid & 3) * 8;
  const size_t rowHalf = (size_t)64 * K;
  unsigned short* lA = &ldsA[w * 512];
  unsigned short* lB = &ldsB[w * 512];

  int aoff[4], boff[4];
#pragma unroll
  for (int m = 0; m < 4; ++m) aoff[m] = (wr * 64 + m * 16 + fr) * 32 + fq * 8;
#pragma unroll
  for (int n = 0; n < 4; ++n) boff[n] = (wc * 64 + n * 16 + fr) * 32 + fq * 8;

  floatx4 acc[4][4] = {};

  for (int k0 = 0; k0 < K; k0 += 32) {
    __syncthreads();
    gld_lds16(pA, lA);
    gld_lds16(pA + rowHalf, lA + 2048);
    gld_lds16(pB, lB);
    gld_lds16(pB + rowHalf, lB + 2048);
    pA += 32; pB += 32;
    asm volatile("s_waitcnt vmcnt(0)" ::: "memory");
    __syncthreads();
    short8v a[4], b[4];
#pragma unroll
    for (int m = 0; m < 4; ++m) a[m] = *(const short8v*)&ldsA[aoff[m]];
#pragma unroll
    for (int n = 0; n < 4; ++n) b[n] = *(const short8v*)&ldsB[boff[n]];
#pragma unroll
    for (int m = 0; m < 4; ++m)
#pragma unroll
      for (int n = 0; n < 4; ++n)
        acc[m][n] = __builtin_amdgcn_mfma_f32_16x16x32_bf16(a[m], b[n], acc[m][n], 0, 0, 0);
  }

  const int r0 = brow + wr * 64 + fq * 4;
  const int c0 = bcol + wc * 64 + fr;
  if (MODE == 0) {
    unsigned short* Cb = (unsigned short*)C;
#pragma unroll
    for (int m = 0; m < 4; ++m)
#pragma unroll
      for (int n = 0; n < 4; ++n)
#pragma unroll
        for (int r = 0; r < 4; ++r)
          Cb[(size_t)(r0 + m * 16 + r) * N + c0 + n * 16] = f2bf(acc[m][n][r]);
  } else if (MODE == 1) {
    unsigned short* Ct = (unsigned short*)C;
#pragma unroll
    for (int m = 0; m < 4; ++m)
#pragma unroll
      for (int n = 0; n < 4; ++n) {
        ushort4 pk;
        pk.x = f2bf(acc[m][n][0]); pk.y = f2bf(acc[m][n][1]);
        pk.z = f2bf(acc[m][n][2]); pk.w = f2bf(acc[m][n][3]);
        *(ushort4*)&Ct[(size_t)(c0 + n * 16) * M + (r0 + m * 16)] = pk;
      }
  } else {
    float* Cf = (float*)C;
#pragma unroll
    for (int m = 0; m < 4; ++m)
#pragma unroll
      for (int n = 0; n < 4; ++n)
#pragma unroll
        for (int r = 0; r < 4; ++r)
          Cf[(size_t)(r0 + m * 16 + r) * N + c0 + n * 16] = acc[m][n][r];
  }
}

// ---------------- RoPE + per-head relayout. In: [s][nh*128] bf16. Out: [nh][s][128] bf16.
// out[j]    = (x[2j]*cos - x[2j+1]*sin) * scale
// out[j+64] = (x[2j+1]*cos + x[2j]*sin) * scale
__global__ __launch_bounds__(256) void rope_kernel(const unsigned short* __restrict__ In,
                                                   const float* __restrict__ cosT,
                                                   const float* __restrict__ sinT,
                                                   unsigned short* __restrict__ Out,
                                                   int nh, float scale) {
  int idx = blockIdx.x * 256 + threadIdx.x;
  int j = idx & 63;
  int s = (idx >> 6) & (S_LEN - 1);
  int h = idx >> 17;
  unsigned int pr = *(const unsigned int*)(In + (size_t)s * (nh * HD) + h * HD + 2 * j);
  float q1 = bf2f((unsigned short)(pr & 0xffffu));
  float q2 = bf2f((unsigned short)(pr >> 16));
  float c = cosT[s * 64 + j], sn = sinT[s * 64 + j];
  unsigned short* op = Out + ((size_t)h * S_LEN + s) * HD + j;
  op[0]  = f2bf(scale * (q1 * c - q2 * sn));
  op[64] = f2bf(scale * (q2 * c + q1 * sn));
}

// ---------------- Flash attention (causal, GQA 4:1).
// grid (32 qtiles, 32 heads), 256 thr. Q pre-scaled by 1/sqrt(128).
// Qr [NH][S][128], Kr [NKV][S][128], Vt [NKV][128][S] (d-major), Ao [S][HID] bf16.
__global__ __launch_bounds__(256) void attn_fwd(const unsigned short* __restrict__ Qr,
                                                const unsigned short* __restrict__ Kr,
                                                const unsigned short* __restrict__ Vt,
                                                unsigned short* __restrict__ Ao) {
  __shared__ unsigned short Kl[64 * 128];   // [kv][128], XOR-swizzled (cb ^ (row&7)<<4)
  __shared__ unsigned short Vl[128 * 64];   // [d][kv],   XOR-swizzled
  __shared__ unsigned short Pl[4][16 * 72]; // per-wave P [16 qrows][64 kv], padded to 72
  const int qt = blockIdx.x, h = blockIdx.y, hk = h >> 2;
  const int qb = qt * 64;
  const int tid = threadIdx.x, w = tid >> 6, lane = tid & 63;
  const int fr = lane & 15, fq = lane >> 4;

  // Q fragments in registers (A-operand): rows qb+w*16+fr, k = ks*32+fq*8
  short8v aq[4];
  {
    const unsigned short* qp = Qr + ((size_t)(h * S_LEN + qb + w * 16 + fr)) * HD + fq * 8;
#pragma unroll
    for (int ks = 0; ks < 4; ++ks) aq[ks] = *(const short8v*)(qp + ks * 32);
  }

  // staging source addresses (pre-swizzled global source, linear LDS dest)
  const int krow = tid >> 4;                                        // K tile: 256B rows
  const int kcb = ((tid & 15) * 16) ^ (((tid >> 4) & 7) << 4);
  const unsigned short* pK0 = Kr + ((size_t)hk * S_LEN + krow) * HD + (kcb >> 1);
  const int vrow = tid >> 3;                                        // V tile: 128B rows
  const int vcb = ((tid & 7) * 16) ^ (((tid >> 3) & 7) << 4);
  const unsigned short* pV0 = Vt + ((size_t)hk * HD + vrow) * S_LEN + (vcb >> 1);

  float m_r[4] = {-1e30f, -1e30f, -1e30f, -1e30f};
  float l_r[4] = {0.f, 0.f, 0.f, 0.f};
  floatx4 o[8] = {};

  const int nt = qt + 1;
  for (int t = 0; t < nt; ++t) {
    const int kv0 = t * 64;
    __syncthreads();
    {
      const unsigned short* pk = pK0 + (size_t)kv0 * HD;
      const unsigned short* pv = pV0 + kv0;
#pragma unroll
      for (int j = 0; j < 4; ++j)
        gld_lds16(pk + (size_t)j * 16 * HD, &Kl[w * 512 + j * 2048]);
#pragma unroll
      for (int j = 0; j < 4; ++j)
        gld_lds16(pv + (size_t)j * 32 * S_LEN, &Vl[w * 512 + j * 2048]);
    }
    asm volatile("s_waitcnt vmcnt(0)" ::: "memory");
    __syncthreads();

    // S = Q K^T  (16 x 64 per wave)
    floatx4 s[4] = {};
#pragma unroll
    for (int ks = 0; ks < 4; ++ks) {
#pragma unroll
      for (int n = 0; n < 4; ++n) {
        int row = n * 16 + fr;
        int cb = (ks * 64 + fq * 16) ^ ((row & 7) << 4);
        short8v bk = *(const short8v*)&Kl[row * 128 + (cb >> 1)];
        s[n] = __builtin_amdgcn_mfma_f32_16x16x32_bf16(aq[ks], bk, s[n], 0, 0, 0);
      }
    }

    if (t == qt) {  // diagonal tile: causal mask
#pragma unroll
      for (int n = 0; n < 4; ++n) {
        int col = kv0 + n * 16 + fr;
#pragma unroll
        for (int r = 0; r < 4; ++r) {
          int rowq = qb + w * 16 + fq * 4 + r;
          if (col > rowq) s[n][r] = -1e30f;
        }
      }
    }

    // online softmax (rows live across 16-lane groups)
    float vmax[4];
#pragma unroll
    for (int r = 0; r < 4; ++r)
      vmax[r] = fmaxf(fmaxf(s[0][r], s[1][r]), fmaxf(s[2][r], s[3][r]));
#pragma unroll
    for (int off = 8; off; off >>= 1)
#pragma unroll
      for (int r = 0; r < 4; ++r)
        vmax[r] = fmaxf(vmax[r], __shfl_xor(vmax[r], off));

    float alpha[4], psum[4] = {0.f, 0.f, 0.f, 0.f};
#pragma unroll
    for (int r = 0; r < 4; ++r) {
      float mn = fmaxf(m_r[r], vmax[r]);
      alpha[r] = __expf(m_r[r] - mn);
      m_r[r] = mn;
    }
#pragma unroll
    for (int n = 0; n < 4; ++n)
#pragma unroll
      for (int r = 0; r < 4; ++r) {
        float p = __expf(s[n][r] - m_r[r]);
        psum[r] += p;
        Pl[w][(fq * 4 + r) * 72 + n * 16 + fr] = f2bf(p);
      }
#pragma unroll
    for (int r = 0; r < 4; ++r) l_r[r] = l_r[r] * alpha[r] + psum[r];
#pragma unroll
    for (int nf = 0; nf < 8; ++nf)
#pragma unroll
      for (int r = 0; r < 4; ++r) o[nf][r] *= alpha[r];

    // O += P V
    short8v pa[2];
#pragma unroll
    for (int ks = 0; ks < 2; ++ks)
      pa[ks] = *(const short8v*)&Pl[w][fr * 72 + ks * 32 + fq * 8];
#pragma unroll
    for (int nf = 0; nf < 8; ++nf) {
#pragma unroll
      for (int ks = 0; ks < 2; ++ks) {
        int row = nf * 16 + fr;
        int cb = (ks * 64 + fq * 16) ^ ((row & 7) << 4);
        short8v bv = *(const short8v*)&Vl[row * 64 + (cb >> 1)];
        o[nf] = __builtin_amdgcn_mfma_f32_16x16x32_bf16(pa[ks], bv, o[nf], 0, 0, 0);
      }
    }
  }

  // normalize + write Ao[s][h*128+d]
  float lsum[4];
#pragma unroll
  for (int r = 0; r < 4; ++r) lsum[r] = l_r[r];
#pragma unroll
  for (int off = 8; off; off >>= 1)
#pragma unroll
    for (int r = 0; r < 4; ++r) lsum[r] += __shfl_xor(lsum[r], off);
  float rinv[4];
#pragma unroll
  for (int r = 0; r < 4; ++r) rinv[r] = 1.0f / lsum[r];

  unsigned short* aop = Ao + (size_t)(qb + w * 16 + fq * 4) * HID + h * HD + fr;
#pragma unroll
  for (int nf = 0; nf < 8; ++nf)
#pragma unroll
    for (int r = 0; r < 4; ++r)
      aop[(size_t)r * HID + nf * 16] = f2bf(o[nf][r] * rinv[r]);
}

// ---------------- launch ----------------
extern "C" void kernel_launch(void* const* d_in, const int* in_sizes, int n_in,
                              void* d_out, int out_size, void* d_ws, size_t ws_size,
                              hipStream_t stream) {
  (void)in_sizes; (void)n_in; (void)out_size; (void)ws_size;
  const float* X    = (const float*)d_in[0];
  const float* cosT = (const float*)d_in[3];
  const float* sinT = (const float*)d_in[4];
  const float* Wq   = (const float*)d_in[5];
  const float* Wk   = (const float*)d_in[6];
  const float* Wv   = (const float*)d_in[7];
  const float* Wo   = (const float*)d_in[8];

  char* ws = (char*)d_ws;
  size_t off = 0;
  auto alloc = [&](size_t bytes) { char* p = ws + off; off += (bytes + 255) & ~(size_t)255; return p; };
  unsigned short* Xb  = (unsigned short*)alloc((size_t)S_LEN * HID * 2);         // X bf16
  unsigned short* Wqb = (unsigned short*)alloc((size_t)HID * HID * 2);           // dead after Q-gemm
  unsigned short* Wkb = (unsigned short*)alloc((size_t)1024 * HID * 2);
  unsigned short* Wvb = (unsigned short*)alloc((size_t)1024 * HID * 2);
  unsigned short* Wob = (unsigned short*)alloc((size_t)HID * HID * 2);
  unsigned short* Qg  = (unsigned short*)alloc((size_t)S_LEN * HID * 2);         // pre-rope Q
  unsigned short* Kg  = (unsigned short*)alloc((size_t)S_LEN * 1024 * 2);        // pre-rope K
  unsigned short* Vt  = (unsigned short*)alloc((size_t)1024 * S_LEN * 2);        // V^T [o][s]
  // aliases (stream-ordered lifetimes):
  unsigned short* Qr = Wqb;                                   // [32][2048][128], after Q-gemm
  unsigned short* Kr = Wqb + (size_t)NH * S_LEN * HD;         // [8][2048][128]
  unsigned short* Ao = Xb;                                    // [2048][4096], after V-gemm

  cvt_f32_bf16<<<2048, 256, 0, stream>>>(X,  Xb,  (S_LEN * HID) / 4);
  cvt_f32_bf16<<<2048, 256, 0, stream>>>(Wq, Wqb, (HID * HID) / 4);
  cvt_f32_bf16<<<1024, 256, 0, stream>>>(Wk, Wkb, (1024 * HID) / 4);
  cvt_f32_bf16<<<1024, 256, 0, stream>>>(Wv, Wvb, (1024 * HID) / 4);
  cvt_f32_bf16<<<2048, 256, 0, stream>>>(Wo, Wob, (HID * HID) / 4);

  gemm_bt<0><<<dim3(32, 16), 256, 0, stream>>>(Xb, Wqb, Qg, S_LEN, HID, HID);
  gemm_bt<0><<<dim3(8, 16),  256, 0, stream>>>(Xb, Wkb, Kg, S_LEN, 1024, HID);
  gemm_bt<1><<<dim3(8, 16),  256, 0, stream>>>(Xb, Wvb, Vt, S_LEN, 1024, HID);

  rope_kernel<<<(NH * S_LEN * 64) / 256, 256, 0, stream>>>(Qg, cosT, sinT, Qr, NH, 0.08838834764831845f);
  rope_kernel<<<(NKV * S_LEN * 64) / 256, 256, 0, stream>>>(Kg, cosT, sinT, Kr, NKV, 1.0f);

  attn_fwd<<<dim3(32, 32), 256, 0, stream>>>(Qr, Kr, Vt, Ao);

  gemm_bt<2><<<dim3(32, 16), 256, 0, stream>>>(Ao, Wob, (float*)d_out, S_LEN, HID, HID);
}